// Round 7
// baseline (191.338 us; speedup 1.0000x reference)
//
#include <hip/hip_runtime.h>
#include <stdint.h>
#include <stddef.h>

// Problem constants
#define SEQ   2048
#define BATCH 2
#define NTOK  (SEQ*BATCH)   // 4096
#define EMB   1024
#define QKVN  3072
#define NH    16
#define HD    64

typedef __bf16 bf16x8 __attribute__((ext_vector_type(8)));
typedef float  f32x4  __attribute__((ext_vector_type(4)));

// fp32 -> bf16 (RNE)
__device__ __forceinline__ unsigned short f2b(float f) {
  union { float f; uint32_t u; } v; v.f = f;
  uint32_t r = v.u + 0x7fffu + ((v.u >> 16) & 1u);
  return (unsigned short)(r >> 16);
}

// async global->LDS, 16B/lane; LDS dest is wave-uniform base + lane*16
#define GLOAD_LDS16(gp, lp)                                                    \
  __builtin_amdgcn_global_load_lds(                                            \
      (__attribute__((address_space(1))) void*)(gp),                           \
      (__attribute__((address_space(3))) void*)(lp), 16, 0, 0)

// ---------------------------------------------------------------- convert
// single fused kernel: x (1048576 float4) + w_qkv (786432) + w_out (262144)
__global__ void cvt3_kernel(const float* __restrict__ x,
                            const float* __restrict__ wq,
                            const float* __restrict__ wo,
                            unsigned short* __restrict__ xb,
                            unsigned short* __restrict__ wqb,
                            unsigned short* __restrict__ wob) {
  int i = blockIdx.x * blockDim.x + threadIdx.x;   // float4 index, exact grid
  const float* in; unsigned short* out; int k;
  if (i < 1048576)              { in = x;  out = xb;  k = i; }
  else if (i < 1048576+786432)  { in = wq; out = wqb; k = i - 1048576; }
  else                          { in = wo; out = wob; k = i - (1048576+786432); }
  float4 v = ((const float4*)in)[k];
  ushort4 o;
  o.x = f2b(v.x); o.y = f2b(v.y); o.z = f2b(v.z); o.w = f2b(v.w);
  ((ushort4*)out)[k] = o;
}

// ---------------------------------------------------------------- GEMM C = A * B^T
// (byte-identical to round 6 — T4 ring-3 counted-vmcnt pipeline)
__global__ __launch_bounds__(256) void gemm_bt(
    const unsigned short* __restrict__ A,
    const unsigned short* __restrict__ B,
    unsigned short* __restrict__ Cb,
    float* __restrict__ Cf,
    const float* __restrict__ bias,
    unsigned short* __restrict__ vt,
    int M, int N, int K, int mode)
{
  __shared__ unsigned short As[3][128*32];   // 3 x 8 KB ring
  __shared__ unsigned short Bs[3][128*32];   // 3 x 8 KB ring

  const int tid  = threadIdx.x;
  const int wave = tid >> 6, lane = tid & 63;
  const int l16  = lane & 15, quad = lane >> 4;
  const int tm = blockIdx.x * 128, tn = blockIdx.y * 128;
  const int wm = (wave & 1) * 64,  wn = (wave >> 1) * 64;

  // staging geometry (per wave: 2 chunks-of-512-shorts per matrix)
  const int e0   = (wave*2 + 0)*512 + lane*8;
  const int e1   = (wave*2 + 1)*512 + lane*8;
  const int row0 = e0 >> 5, kk0a = e0 & 31;
  const int row1 = e1 >> 5, kk1a = e1 & 31;
  const int ld0  = (wave*2 + 0)*512;
  const int ld1  = (wave*2 + 1)*512;

#define GSTAGE(bf, k0s)                                                        \
  do {                                                                         \
    GLOAD_LDS16(A + (size_t)(tm + row0)*K + ((k0s) + kk0a), As[bf] + ld0);     \
    GLOAD_LDS16(B + (size_t)(tn + row0)*K + ((k0s) + kk0a), Bs[bf] + ld0);     \
    GLOAD_LDS16(A + (size_t)(tm + row1)*K + ((k0s) + kk1a), As[bf] + ld1);     \
    GLOAD_LDS16(B + (size_t)(tn + row1)*K + ((k0s) + kk1a), Bs[bf] + ld1);     \
  } while (0)

  f32x4 acc[4][4] = {};
  const int nst = K >> 5;                 // K-steps of 32 (K=1024 -> 32)

  GSTAGE(0, 0);
  GSTAGE(1, 32);

  int b0i = 0, b1i = 1, b2i = 2;
  for (int t = 0; t < nst; ++t) {
    if (t + 2 < nst) GSTAGE(b2i, (t + 2)*32);   // outstanding now: 12

    if (t + 2 < nst)      asm volatile("s_waitcnt vmcnt(8)" ::: "memory");
    else if (t + 1 < nst) asm volatile("s_waitcnt vmcnt(4)" ::: "memory");
    else                  asm volatile("s_waitcnt vmcnt(0)" ::: "memory");
    __builtin_amdgcn_s_barrier();               // all waves' tile-t staged
    __builtin_amdgcn_sched_barrier(0);          // pin reads below barrier

    const unsigned short* Ac = As[b0i];
    const unsigned short* Bc = Bs[b0i];
    bf16x8 af[4], bf[4];
#pragma unroll
    for (int i = 0; i < 4; ++i) {
      af[i] = *(const bf16x8*)(Ac + (wm + i*16 + l16)*32 + quad*8);
      bf[i] = *(const bf16x8*)(Bc + (wn + i*16 + l16)*32 + quad*8);
    }
#pragma unroll
    for (int mi = 0; mi < 4; ++mi)
#pragma unroll
      for (int ni = 0; ni < 4; ++ni)
        acc[mi][ni] = __builtin_amdgcn_mfma_f32_16x16x32_bf16(af[mi], bf[ni], acc[mi][ni], 0, 0, 0);

    __builtin_amdgcn_s_barrier();               // close reads of buf b0i
    __builtin_amdgcn_sched_barrier(0);
    const int tmp = b0i; b0i = b1i; b1i = b2i; b2i = tmp;
  }
#undef GSTAGE

  // epilogue: C/D layout col=lane&15, row=quad*4+reg
  if (mode == 1) {
#pragma unroll
    for (int mi = 0; mi < 4; ++mi)
#pragma unroll
      for (int ni = 0; ni < 4; ++ni)
#pragma unroll
        for (int r = 0; r < 4; ++r) {
          const int row = tm + wm + mi*16 + quad*4 + r;
          const int col = tn + wn + ni*16 + l16;
          Cf[(size_t)row*N + col] = acc[mi][ni][r] + bias[col];
        }
  } else {  // mode 2
    if (tn < 2048) {
#pragma unroll
      for (int mi = 0; mi < 4; ++mi)
#pragma unroll
        for (int ni = 0; ni < 4; ++ni)
#pragma unroll
          for (int r = 0; r < 4; ++r) {
            const int row = tm + wm + mi*16 + quad*4 + r;
            const int col = tn + wn + ni*16 + l16;
            Cb[(size_t)row*2048 + col] = f2b(acc[mi][ni][r]);
          }
    } else {
#pragma unroll
      for (int mi = 0; mi < 4; ++mi)
#pragma unroll
        for (int ni = 0; ni < 4; ++ni) {
          const int f     = tn + wn + ni*16 + l16 - 2048;  // h*64+d
          const int row0_ = tm + wm + mi*16 + quad*4;      // token (4-aligned)
          const int bb    = row0_ >> 11;
          const int n0    = row0_ & 2047;
          ushort4 pv;
          pv.x = f2b(acc[mi][ni][0]); pv.y = f2b(acc[mi][ni][1]);
          pv.z = f2b(acc[mi][ni][2]); pv.w = f2b(acc[mi][ni][3]);
          *(ushort4*)(vt + ((size_t)(bb*1024 + f))*2048 + n0) = pv;
        }
    }
  }
}

// ---------------------------------------------------------------- attention
// LDS-PIPE FIX (round 7): attn was LDS-throughput-bound — 22 DS instrs per
// wave-body serving only 16 MFMA = ~89% LDS-pipe busy per CU (m134: b128 ~12cy).
// Restore nf=2 (wave = 32 q-rows): the same K/V/P reads now feed 32 MFMA
// (28 DS instrs / body) -> per-work LDS traffic x0.64 and total DS instr
// count per CU halves (waves halve). Block = 128 q-rows, grid 512 (8 xcd x
// 4 bh x 16 qtiles). Occupancy drops to 8 waves/CU — proven free (r1/r2).
// Everything else kept: two-stream body, quad-buffered K/V, XCD remap,
// static-offset softmax p = exp(s - 12) (cancels in ratio).
__global__ __launch_bounds__(256) void attn_kernel(
    const unsigned short* __restrict__ qk,
    const unsigned short* __restrict__ vT,
    unsigned short* __restrict__ aout)      // [4096][1024]
{
  __shared__ unsigned short Ks[4][32*64];   // [buf][key][dslot]      4x4 KB
  __shared__ unsigned short Vt[4][64*32];   // [buf][d][keyslot^swz]  4x4 KB
  __shared__ unsigned short Pl[4*2*32*32];  // [wave][stream][qrow][key^swz] 16 KB

  const int tid  = threadIdx.x;
  const int wave = tid >> 6, lane = tid & 63;
  const int l16  = lane & 15, quad = lane >> 4;

  // XCD-aware remap: 512 blocks = 8 xcd * 4 heads * 16 q-tiles (bijective)
  const int flat = blockIdx.x;
  const int xcd  = flat & 7;
  const int idx  = flat >> 3;             // 0..63 within xcd
  const int bh   = xcd*4 + (idx >> 4);    // 4 (b,h) pairs per XCD
  const int qt   = idx & 15;              // 16 q-tiles of 128 rows
  const int b  = bh >> 4, h = bh & 15;
  const size_t tok0 = (size_t)b * SEQ;
  const int qrow0 = qt*128 + wave*32;
  const int ksw = l16 & 7;                // K chunk swizzle (8 chunks/row)
  const int xsw = (l16 >> 1) & 3;         // V/P chunk swizzle (4 chunks/row)

  // staging geometry: per tile 256 chunks of 16B; wave w owns chunks w*64+lane
  const int p     = wave*64 + lane;
  const int krow  = p >> 3;                         // key row (8 chunks/row)
  const int kc    = ((p & 7) ^ (krow & 7)) << 3;    // swizzled src col (shorts)
  const int vd    = p >> 2;                         // d row (4 chunks/row)
  const int vc    = ((p & 3) ^ ((vd >> 1) & 3)) << 3;
  const unsigned short* kbase = qk + tok0*2048 + 1024 + h*64;
  const unsigned short* vbase = vT + ((size_t)(b*1024 + h*64))*2048;
  const int ldstw = wave*512;                       // wave-uniform LDS offset

#define STAGE(bf, t)                                                          \
  do {                                                                        \
    const int _kk = (t)*32;                                                   \
    GLOAD_LDS16(kbase + (size_t)(_kk + krow)*2048 + kc, &Ks[bf][ldstw]);      \
    GLOAD_LDS16(vbase + (size_t)vd*2048 + _kk + vc,     &Vt[bf][ldstw]);      \
  } while (0)

  // Q fragments (B operand: B[n=nf*16+l16][k=quad*8+j]), pre-scaled by 0.125
  bf16x8 qf[2][2];
#pragma unroll
  for (int nf = 0; nf < 2; ++nf) {
    const unsigned short* qp = qk + (tok0 + qrow0 + nf*16 + l16)*2048 + h*64;
#pragma unroll
    for (int ks = 0; ks < 2; ++ks) {
      bf16x8 t = *(const bf16x8*)(qp + ks*32 + quad*8);
#pragma unroll
      for (int j = 0; j < 8; ++j) t[j] = (__bf16)((float)t[j] * 0.125f);
      qf[nf][ks] = t;
    }
  }

  f32x4 oacc[4][2] = {};
  float l0 = 0.f, l1 = 0.f;
  unsigned short* Pw0 = Pl + (wave*2 + 0)*1024;
  unsigned short* Pw1 = Pl + (wave*2 + 1)*1024;
  const float LOG2E = 1.44269504f;
  const float OFF2  = 17.3123405f;   // 12 * log2(e)

  // prologue: stage tiles 0,1 into bufs 0,1
  STAGE(0, 0);
  STAGE(1, 1);
  __syncthreads();

  for (int kbb = 0; kbb < SEQ/64; ++kbb) {      // 32 bodies, 2 tiles each
    const int t0 = kbb*2;
    const int b0 = t0 & 3, b1 = (t0 + 1) & 3;
    // prefetch 2 tiles ahead (bufs disjoint from b0/b1; barrier-protected)
    if (t0 + 2 < SEQ/32) { STAGE((t0+2)&3, t0+2); STAGE((t0+3)&3, t0+3); }

    // ---- QK^T both streams: D[m=key(32)][n=qrow(32)]
    f32x4 sA[2][2] = {}, sB[2][2] = {};
    __builtin_amdgcn_s_setprio(1);
#pragma unroll
    for (int ks = 0; ks < 2; ++ks)
#pragma unroll
      for (int mf = 0; mf < 2; ++mf) {
        bf16x8 kf = *(const bf16x8*)(&Ks[b0][(mf*16 + l16)*64 + (((ks*4 + quad) ^ ksw) << 3)]);
        sA[mf][0] = __builtin_amdgcn_mfma_f32_16x16x32_bf16(kf, qf[0][ks], sA[mf][0], 0, 0, 0);
        sA[mf][1] = __builtin_amdgcn_mfma_f32_16x16x32_bf16(kf, qf[1][ks], sA[mf][1], 0, 0, 0);
      }
#pragma unroll
    for (int ks = 0; ks < 2; ++ks)
#pragma unroll
      for (int mf = 0; mf < 2; ++mf) {
        bf16x8 kf = *(const bf16x8*)(&Ks[b1][(mf*16 + l16)*64 + (((ks*4 + quad) ^ ksw) << 3)]);
        sB[mf][0] = __builtin_amdgcn_mfma_f32_16x16x32_bf16(kf, qf[0][ks], sB[mf][0], 0, 0, 0);
        sB[mf][1] = __builtin_amdgcn_mfma_f32_16x16x32_bf16(kf, qf[1][ks], sB[mf][1], 0, 0, 0);
      }
    __builtin_amdgcn_s_setprio(0);

    // ---- softmax A -> Pw0
#pragma unroll
    for (int nf = 0; nf < 2; ++nf) {
      float rs = nf ? l1 : l0;
#pragma unroll
      for (int mf = 0; mf < 2; ++mf) {
        union { float f; uint32_t u; } a0, a1, a2, a3;
        a0.f = __builtin_amdgcn_exp2f(fmaf(sA[mf][nf][0], LOG2E, -OFF2));
        a1.f = __builtin_amdgcn_exp2f(fmaf(sA[mf][nf][1], LOG2E, -OFF2));
        a2.f = __builtin_amdgcn_exp2f(fmaf(sA[mf][nf][2], LOG2E, -OFF2));
        a3.f = __builtin_amdgcn_exp2f(fmaf(sA[mf][nf][3], LOG2E, -OFF2));
        rs += (a0.f + a1.f) + (a2.f + a3.f);
        uint2 pk;
        pk.x = __builtin_amdgcn_perm(a1.u, a0.u, 0x07060302u);
        pk.y = __builtin_amdgcn_perm(a3.u, a2.u, 0x07060302u);
        *(uint2*)(Pw0 + (nf*16 + l16)*32 + ((((mf*2 + (quad>>1)) ^ xsw) << 3) + (quad&1)*4)) = pk;
      }
      if (nf) l1 = rs; else l0 = rs;
    }
    // ---- PV A: O^T += V^T P^T (k=32 keys; vf shared across nf)
    __builtin_amdgcn_s_setprio(1);
    {
      bf16x8 pf0 = *(const bf16x8*)(Pw0 + l16*32 + ((quad ^ xsw) << 3));
      bf16x8 pf1 = *(const bf16x8*)(Pw0 + (16 + l16)*32 + ((quad ^ xsw) << 3));
#pragma unroll
      for (int mf = 0; mf < 4; ++mf) {
        bf16x8 vf = *(const bf16x8*)(&Vt[b0][(mf*16 + l16)*32 + ((quad ^ xsw) << 3)]);
        oacc[mf][0] = __builtin_amdgcn_mfma_f32_16x16x32_bf16(vf, pf0, oacc[mf][0], 0, 0, 0);
        oacc[mf][1] = __builtin_amdgcn_mfma_f32_16x16x32_bf16(vf, pf1, oacc[mf][1], 0, 0, 0);
      }
    }
    __builtin_amdgcn_s_setprio(0);

    // ---- softmax B -> Pw1
#pragma unroll
    for (int nf = 0; nf < 2; ++nf) {
      float rs = nf ? l1 : l0;
#pragma unroll
      for (int mf = 0; mf < 2; ++mf) {
        union { float f; uint32_t u; } a0, a1, a2, a3;
        a0.f = __builtin_amdgcn_exp2f(fmaf(sB[mf][nf][0], LOG2E, -OFF2));
        a1.f = __builtin_amdgcn_exp2f(fmaf(sB[mf][nf][1], LOG2E, -OFF2));
        a2.f = __builtin_amdgcn_exp2f(fmaf(sB[mf][nf][2], LOG2E, -OFF2));
        a3.f = __builtin_amdgcn_exp2f(fmaf(sB[mf][nf][3], LOG2E, -OFF2));
        rs += (a0.f + a1.f) + (a2.f + a3.f);
        uint2 pk;
        pk.x = __builtin_amdgcn_perm(a1.u, a0.u, 0x07060302u);
        pk.y = __builtin_amdgcn_perm(a3.u, a2.u, 0x07060302u);
        *(uint2*)(Pw1 + (nf*16 + l16)*32 + ((((mf*2 + (quad>>1)) ^ xsw) << 3) + (quad&1)*4)) = pk;
      }
      if (nf) l1 = rs; else l0 = rs;
    }
    // ---- PV B
    __builtin_amdgcn_s_setprio(1);
    {
      bf16x8 pf0 = *(const bf16x8*)(Pw1 + l16*32 + ((quad ^ xsw) << 3));
      bf16x8 pf1 = *(const bf16x8*)(Pw1 + (16 + l16)*32 + ((quad ^ xsw) << 3));
#pragma unroll
      for (int mf = 0; mf < 4; ++mf) {
        bf16x8 vf = *(const bf16x8*)(&Vt[b1][(mf*16 + l16)*32 + ((quad ^ xsw) << 3)]);
        oacc[mf][0] = __builtin_amdgcn_mfma_f32_16x16x32_bf16(vf, pf0, oacc[mf][0], 0, 0, 0);
        oacc[mf][1] = __builtin_amdgcn_mfma_f32_16x16x32_bf16(vf, pf1, oacc[mf][1], 0, 0, 0);
      }
    }
    __builtin_amdgcn_s_setprio(0);

    // one barrier per body (2 tiles): implicit vmcnt(0) waits my prefetch
    __syncthreads();
  }
#undef STAGE

  // final l reduce (keys spread over quad) + store O^T -> aout[token][h*64+d]
#pragma unroll
  for (int nf = 0; nf < 2; ++nf) {
    float l = nf ? l1 : l0;
    l += __shfl_xor(l, 16);
    l += __shfl_xor(l, 32);
    const float inv = 1.0f / l;
    const size_t trow = tok0 + qrow0 + nf*16 + l16;
#pragma unroll
    for (int mf = 0; mf < 4; ++mf) {
      ushort4 ov;
      ov.x = f2b(oacc[mf][nf][0] * inv);
      ov.y = f2b(oacc[mf][nf][1] * inv);
      ov.z = f2b(oacc[mf][nf][2] * inv);
      ov.w = f2b(oacc[mf][nf][3] * inv);
      *(ushort4*)(aout + trow*EMB + h*64 + mf*16 + quad*4) = ov;
    }
  }
}

// ---------------------------------------------------------------- launch
extern "C" void kernel_launch(void* const* d_in, const int* in_sizes, int n_in,
                              void* d_out, int out_size, void* d_ws, size_t ws_size,
                              hipStream_t stream) {
  const float* x     = (const float*)d_in[0];
  const float* w_qkv = (const float*)d_in[1];
  const float* w_out = (const float*)d_in[2];
  const float* b_out = (const float*)d_in[3];

  char* ws = (char*)d_ws;
  unsigned short* xb    = (unsigned short*)(ws);                    //  8 MB
  unsigned short* wqkvb = (unsigned short*)(ws + 8388608);          //  6 MB
  unsigned short* woutb = (unsigned short*)(ws + 14680064);         //  2 MB
  unsigned short* qkb   = (unsigned short*)(ws + 16777216);         // 16 MB [4096][2048]
  unsigned short* vTb   = (unsigned short*)(ws + 33554432);         //  8 MB [2048][2048]
  unsigned short* aob   = (unsigned short*)(ws + 41943040);         //  8 MB

  // fused bf16 conversion: 2097152 float4 total, exact 8192x256 grid
  cvt3_kernel<<<8192, 256, 0, stream>>>(x, w_qkv, w_out, xb, wqkvb, woutb);

  // qkv = x @ w_qkv^T : Q,K -> qkb rows (stride 2048), V -> vTb transposed
  gemm_bt<<<dim3(NTOK/128, QKVN/128), 256, 0, stream>>>(
      xb, wqkvb, qkb, nullptr, nullptr, vTb, NTOK, QKVN, EMB, 2);

  // attention: 512 one-dim blocks (XCD-remapped inside kernel)
  attn_kernel<<<dim3(512), 256, 0, stream>>>(qkb, vTb, aob);

  // out = attn @ w_out^T + b_out -> f32 d_out
  gemm_bt<<<dim3(NTOK/128, EMB/128), 256, 0, stream>>>(
      aob, woutb, nullptr, (float*)d_out, b_out, nullptr, NTOK, EMB, EMB, 1);
}